// Round 1
// baseline (238.153 us; speedup 1.0000x reference)
//
#include <hip/hip_runtime.h>

// Problem constants (fixed by reference)
#define BB 16
#define CC 256
#define HH 100
#define WW 100
#define NN 100
#define RH 40
#define RW 40
#define KK 599   // num classes
#define KT 19    // ceil(599/32) k-tiles for transpose
#define CT 8     // 256/32 c-tiles

// Fused: bilinear resize (100x100 -> 40x40, half-pixel) into LDS, per-box
// average pooling via direct region sum (boxes are <=5x5 cells), per-class
// scatter-mean into LDS, write means.
// ws_mode=1: write dst[b][c][k] (coalesced along k, for transpose pass)
// ws_mode=0: write dst[b][k][c] directly (scattered 4B stores; fallback only)
__global__ __launch_bounds__(256) void pool_kernel(
    const float* __restrict__ feat, const float* __restrict__ boxes,
    const int* __restrict__ cls, float* __restrict__ dst, int ws_mode)
{
    __shared__ float tile[RH][RW + 1];  // +1 pad: random per-box LDS reads
    __shared__ float sums[KK];
    __shared__ float cnts[KK];

    const int blk = blockIdx.x;
    const int b = blk >> 8;       // / 256
    const int c = blk & 255;
    const int tid = threadIdx.x;

    const float* __restrict__ src = feat + (size_t)(b * CC + c) * (HH * WW);

    // ---- bilinear resize into LDS ----
    // src coord = (o+0.5)*2.5 - 0.5 = 2.5*o + 0.75 ; always interior.
    // i0 = (5o+1)>>1 ; frac = 0.75 (o even) / 0.25 (o odd)
    for (int idx = tid; idx < RH * RW; idx += 256) {
        int oy = idx / RW;
        int ox = idx - oy * RW;
        int iy0 = (5 * oy + 1) >> 1;
        int ix0 = (5 * ox + 1) >> 1;
        float fy = (oy & 1) ? 0.25f : 0.75f;
        float fx = (ox & 1) ? 0.25f : 0.75f;
        const float* r0 = src + iy0 * WW + ix0;
        float v00 = r0[0], v01 = r0[1];
        float v10 = r0[WW], v11 = r0[WW + 1];
        float top = (1.0f - fx) * v00 + fx * v01;
        float bot = (1.0f - fx) * v10 + fx * v11;
        tile[oy][ox] = (1.0f - fy) * top + fy * bot;
    }

    for (int k = tid; k < KK; k += 256) {
        sums[k] = 0.0f;
        cnts[k] = 0.0f;
    }
    __syncthreads();

    // ---- per-box pooling + class scatter (threads 0..99) ----
    if (tid < NN) {
        const float* bp = boxes + (size_t)(b * NN + tid) * 4;
        const float sc = 0.0390625f;  // 40/1024 = 5/128, exact
        // rintf -> v_rndne_f32: round half to even, matches jnp.round
        int x1 = (int)rintf(bp[0] * sc);
        int y1 = (int)rintf(bp[1] * sc);
        int x2 = (int)rintf(bp[2] * sc);
        int y2 = (int)rintf(bp[3] * sc);
        x1 = max(x1, 0); y1 = max(y1, 0);
        x2 = min(x2, RW); y2 = min(y2, RH);
        if (x1 < x2 && y1 < y2) {
            float s = 0.0f;
            for (int y = y1; y < y2; ++y)
                for (int x = x1; x < x2; ++x)
                    s += tile[y][x];
            float area = (float)((y2 - y1) * (x2 - x1));
            int k = cls[b * NN + tid];
            atomicAdd(&sums[k], s / area);
            atomicAdd(&cnts[k], 1.0f);
        }
    }
    __syncthreads();

    // ---- write per-class means ----
    if (ws_mode) {
        float* o = dst + (size_t)(b * CC + c) * KK;
        for (int k = tid; k < KK; k += 256) {
            float cn = cnts[k];
            o[k] = (cn > 0.0f) ? (sums[k] / cn) : 0.0f;
        }
    } else {
        for (int k = tid; k < KK; k += 256) {
            float cn = cnts[k];
            dst[(size_t)(b * KK + k) * CC + c] = (cn > 0.0f) ? (sums[k] / cn) : 0.0f;
        }
    }
}

// Transpose ws[b][c][k] -> out[b][k][c], 32x32 LDS tiles, both sides coalesced.
__global__ __launch_bounds__(256) void transpose_kernel(
    const float* __restrict__ ws, float* __restrict__ out)
{
    __shared__ float t[32][33];
    int blk = blockIdx.x;
    int b = blk / (KT * CT);
    int r = blk - b * (KT * CT);
    int kt = r / CT;
    int ct = r - kt * CT;
    int k0 = kt * 32;
    int c0 = ct * 32;
    int tx = threadIdx.x & 31;
    int ty = threadIdx.x >> 5;  // 0..7

    int k = k0 + tx;
    if (k < KK) {
        #pragma unroll
        for (int i = 0; i < 4; ++i) {
            int cl = ty + i * 8;
            t[cl][tx] = ws[(size_t)(b * CC + c0 + cl) * KK + k];
        }
    }
    __syncthreads();
    #pragma unroll
    for (int i = 0; i < 4; ++i) {
        int kl = ty + i * 8;
        int kk = k0 + kl;
        if (kk < KK)
            out[(size_t)(b * KK + kk) * CC + c0 + tx] = t[tx][kl];
    }
}

extern "C" void kernel_launch(void* const* d_in, const int* in_sizes, int n_in,
                              void* d_out, int out_size, void* d_ws, size_t ws_size,
                              hipStream_t stream) {
    const float* feat  = (const float*)d_in[0];
    const float* boxes = (const float*)d_in[1];
    const int*   cls   = (const int*)d_in[2];
    float* out = (float*)d_out;

    const size_t ws_need = (size_t)BB * CC * KK * sizeof(float);
    if (ws_size >= ws_need) {
        float* ws = (float*)d_ws;
        pool_kernel<<<BB * CC, 256, 0, stream>>>(feat, boxes, cls, ws, 1);
        transpose_kernel<<<BB * KT * CT, 256, 0, stream>>>(ws, out);
    } else {
        // fallback: direct scattered writes (correct, slower)
        pool_kernel<<<BB * CC, 256, 0, stream>>>(feat, boxes, cls, out, 0);
    }
}